// Round 12
// baseline (391.252 us; speedup 1.0000x reference)
//
#include <hip/hip_runtime.h>
#include <hip/hip_bf16.h>

#define DIM 512
#define BATCH 512
#define CCLS 100000
#define BM 128
#define BN 128
#define NT 782   // ceil(100000/128)

typedef __attribute__((ext_vector_type(4))) float f32x4;
typedef __attribute__((ext_vector_type(2))) long long ll2;

__device__ __forceinline__ void async_copy16(const unsigned char* g, unsigned char* l) {
  __builtin_amdgcn_global_load_lds((const __attribute__((address_space(1))) void*)g,
                                   (__attribute__((address_space(3))) void*)l, 16, 0, 0);
}

// One wave per row: read fp32 row, L2-normalize (fp32), write fp8 e4m3 row
// in QUAD-GROUPED layout: lane l's 8 bytes (k in [8l,8l+8)) land at byte
// (l&3)*128 + (l>>2)*8, i.e. k for MFMA-quad q, k-slice s at q*128 + s*8.
// This lets the GEMM fetch two k-slices per ds_read_b128.
__global__ __launch_bounds__(256) void rownorm_fp8(const float* __restrict__ wt,
                                                   const float* __restrict__ x,
                                                   unsigned char* __restrict__ wn,
                                                   unsigned char* __restrict__ xn) {
  int wave = threadIdx.x >> 6;
  int lane = threadIdx.x & 63;
  int row4 = blockIdx.x * 4 + wave;
  const float* in;
  unsigned char* out;
  int row;
  if (row4 < CCLS) { in = wt; out = wn; row = row4; }
  else             { in = x;  out = xn; row = row4 - CCLS; }
  const float4* src = (const float4*)(in + (size_t)row * DIM);
  float4 v0 = src[2 * lane];
  float4 v1 = src[2 * lane + 1];
  float ss = v0.x*v0.x + v0.y*v0.y + v0.z*v0.z + v0.w*v0.w
           + v1.x*v1.x + v1.y*v1.y + v1.z*v1.z + v1.w*v1.w;
  #pragma unroll
  for (int off = 32; off > 0; off >>= 1) ss += __shfl_xor(ss, off, 64);
  float r = 1.0f / fmaxf(sqrtf(ss), 1e-12f);
  int p0 = __builtin_amdgcn_cvt_pk_fp8_f32(v0.x * r, v0.y * r, 0, false);
  p0     = __builtin_amdgcn_cvt_pk_fp8_f32(v0.z * r, v0.w * r, p0, true);
  int p1 = __builtin_amdgcn_cvt_pk_fp8_f32(v1.x * r, v1.y * r, 0, false);
  p1     = __builtin_amdgcn_cvt_pk_fp8_f32(v1.z * r, v1.w * r, p1, true);
  // quad-grouped permuted store (8B granule): int2 slot = (l&3)*16 + (l>>2)
  ((int2*)(out + (size_t)row * DIM))[(lane & 3) * 16 + (lane >> 2)] = make_int2(p0, p1);
}

// 128x128 full-K fp8 GEMM + CosFace epilogue. ZERO in-loop barriers:
// K=512 fp8 = 512 B/row, so both tiles fit LDS whole (64+64 = 128 KB).
// One prologue stage + one __syncthreads, then 8 waves free-run through
// 8 slice-pairs x 16 MFMA = 128 MFMA/wave with no synchronization --
// the 11-round invariant (~100 us for every barriered K-loop variant at
// a 26 us MFMA floor) was lockstep stall, not staging latency (R11's
// counted-vmcnt null proved that).
// LDS chunk (row m, quad q, slot u') holds global chunk u = u'^(m&7):
// b128 fragment reads at u^(r&7) spread 64 lanes evenly over the 8
// 16B-slot positions (b128 floor rate). Each b128 = slices 2u, 2u+1.
// 8 waves (2m x 4n), per-wave 64x32, acc[4][2] = 32 AGPR; (512,2) cap-256
// (no spill risk; occupancy is LDS-bound at 1 block/CU anyway).
__global__ __launch_bounds__(512, 2) void cosface_gemm(
    const unsigned char* __restrict__ xn,
    const unsigned char* __restrict__ wn,
    const int* __restrict__ gt,
    float* __restrict__ partial,
    float* __restrict__ tgt) {
  __shared__ __align__(16) unsigned char lds_a[BM * DIM];   // 64 KB
  __shared__ __align__(16) unsigned char lds_b[BN * DIM];   // 64 KB
  __shared__ float lds_rowsum[BM];
  __shared__ int lds_gt[BM];

  const int tid = threadIdx.x;
  const int lane = tid & 63;
  const int w = tid >> 6;          // wave 0..7
  const int wm = w >> 2;           // 0..1  (64-row slice)
  const int wn_ = w & 3;           // 0..3  (32-col slice)

  // Bijective XCD swizzle: 3128 = 8 * 391; the 4 mt-siblings of one nt are
  // f-consecutive on one XCD -> wn tile L2-shared.
  int flat = blockIdx.x;
  int f = (flat & 7) * 391 + (flat >> 3);
  const int mt = f & 3;            // 0..3
  const int nt = f >> 2;           // 0..781

  if (tid < BM) {
    lds_rowsum[tid] = 0.f;
    lds_gt[tid] = gt[mt * BM + tid];
  }

  // ---- Prologue staging: 4096 chunks per matrix, 8/thread, linear dest.
  // chunk c: row m = c>>5, quad q = (c>>3)&3, slot u' = c&7;
  // source content chunk u = u' ^ (m&7) within the row's q-block.
  #pragma unroll
  for (int j = 0; j < 8; ++j) {
    int c = j * 512 + tid;
    int m = c >> 5;
    int q = (c >> 3) & 3;
    int up = c & 7;
    unsigned int srcA = (unsigned int)(mt * BM + m) * DIM + q * 128 + ((up ^ (m & 7)) << 4);
    async_copy16(xn + srcA, &lds_a[c * 16]);
  }
  #pragma unroll
  for (int j = 0; j < 8; ++j) {
    int c = j * 512 + tid;
    int m = c >> 5;
    int q = (c >> 3) & 3;
    int up = c & 7;
    int rowB = nt * BN + m;
    if (rowB >= CCLS) rowB = CCLS - 1;   // clamp; excluded in epilogue
    unsigned int srcB = (unsigned int)rowB * DIM + q * 128 + ((up ^ (m & 7)) << 4);
    async_copy16(wn + srcB, &lds_b[c * 16]);
  }
  __syncthreads();   // the ONLY pre-epilogue barrier

  f32x4 acc[4][2];
  #pragma unroll
  for (int i = 0; i < 4; ++i)
    #pragma unroll
    for (int j = 0; j < 2; ++j)
      acc[i][j] = (f32x4){0.f, 0.f, 0.f, 0.f};

  const int quad = lane >> 4;
  const int l15 = lane & 15;
  const int sw = l15 & 7;          // row&7: constant across i*16 offsets

  // ---- Compute: 8 slice-pairs, no barriers. b128 -> slices 2u (lo 8B)
  // and 2u+1 (hi 8B) for this lane's quad.
  #pragma unroll
  for (int u = 0; u < 8; ++u) {
    const int slot = ((u ^ sw) << 4) + quad * 128;
    ll2 a2[4], b2[2];
    #pragma unroll
    for (int i = 0; i < 4; ++i)
      a2[i] = *(const ll2*)&lds_a[(wm * 64 + i * 16 + l15) * DIM + slot];
    #pragma unroll
    for (int j = 0; j < 2; ++j)
      b2[j] = *(const ll2*)&lds_b[(wn_ * 32 + j * 16 + l15) * DIM + slot];
    #pragma unroll
    for (int i = 0; i < 4; ++i)
      #pragma unroll
      for (int j = 0; j < 2; ++j) {
        acc[i][j] = __builtin_amdgcn_mfma_f32_16x16x32_fp8_fp8(a2[i][0], b2[j][0], acc[i][j], 0, 0, 0);
        acc[i][j] = __builtin_amdgcn_mfma_f32_16x16x32_fp8_fp8(a2[i][1], b2[j][1], acc[i][j], 0, 0, 0);
      }
  }

  // ---- Epilogue (R0's verified form): logit = 64*cos (-22.4 at gt);
  // rowsum += sum_n exp(logit-64).
  #pragma unroll
  for (int i = 0; i < 4; ++i) {
    #pragma unroll
    for (int reg = 0; reg < 4; ++reg) {
      int m_loc = wm * 64 + i * 16 + quad * 4 + reg;
      int m_g = mt * BM + m_loc;
      int gtm = lds_gt[m_loc];
      float s = 0.f;
      #pragma unroll
      for (int j = 0; j < 2; ++j) {
        int n_g = nt * BN + wn_ * 32 + j * 16 + l15;
        float logit = 64.f * acc[i][j][reg];
        if (n_g == gtm) {
          logit -= 64.f * 0.35f;
          tgt[m_g] = logit;
        }
        if (n_g < CCLS) s += __expf(logit - 64.f);
      }
      #pragma unroll
      for (int off = 1; off < 16; off <<= 1) s += __shfl_xor(s, off, 64);
      if (l15 == 0) atomicAdd(&lds_rowsum[m_loc], s);
    }
  }
  __syncthreads();
  if (tid < BM)
    partial[(size_t)(mt * BM + tid) * NT + nt] = lds_rowsum[tid];
}

// One wave per row m: sum partial[m][0..NT) (contiguous), emit nll[m].
__global__ __launch_bounds__(64) void nll_rows(const float* __restrict__ partial,
                                               const float* __restrict__ tgt,
                                               float* __restrict__ nll) {
  int m = blockIdx.x;
  int lane = threadIdx.x;
  const float* row = partial + (size_t)m * NT;
  float s = 0.f;
  for (int t = lane; t < NT; t += 64) s += row[t];
  #pragma unroll
  for (int off = 32; off > 0; off >>= 1) s += __shfl_xor(s, off, 64);
  if (lane == 0) nll[m] = (logf(s) + 64.f) - tgt[m];
}

__global__ __launch_bounds__(512) void reduce_mean(const float* __restrict__ nll,
                                                   float* __restrict__ out) {
  __shared__ float red[BATCH];
  int m = threadIdx.x;
  red[m] = nll[m];
  __syncthreads();
  for (int k = 256; k > 0; k >>= 1) {
    if (m < k) red[m] += red[m + k];
    __syncthreads();
  }
  if (m == 0) out[0] = red[0] * (1.0f / BATCH);
}

extern "C" void kernel_launch(void* const* d_in, const int* in_sizes, int n_in,
                              void* d_out, int out_size, void* d_ws, size_t ws_size,
                              hipStream_t stream) {
  const float* x  = (const float*)d_in[0];
  const int*   gt = (const int*)d_in[1];
  const float* wt = (const float*)d_in[2];
  float* out = (float*)d_out;

  char* ws = (char*)d_ws;
  unsigned char* wn = (unsigned char*)ws;                      //  51,200,000 B
  unsigned char* xn = (unsigned char*)(ws + 51200000);         //     262,144 B
  float* partial    = (float*)(ws + 51462144);                 //   1,601,536 B
  float* tgt        = (float*)(ws + 53063680);                 //       2,048 B
  float* nll        = (float*)(ws + 53065728);                 //       2,048 B

  rownorm_fp8<<<(CCLS + BATCH) / 4, 256, 0, stream>>>(wt, x, wn, xn);
  cosface_gemm<<<4 * NT, 512, 0, stream>>>(xn, wn, gt, partial, tgt);
  nll_rows<<<BATCH, 64, 0, stream>>>(partial, tgt, nll);
  reduce_mean<<<1, BATCH, 0, stream>>>(nll, out);
}

// Round 13
// 363.265 us; speedup vs baseline: 1.0770x; 1.0770x over previous
//
#include <hip/hip_runtime.h>
#include <hip/hip_bf16.h>

#define DIM 512
#define BATCH 512
#define CCLS 100000
#define BN 64
#define NT 1563   // ceil(100000/64)

typedef __attribute__((ext_vector_type(4))) float f32x4;

__device__ __forceinline__ void async_copy16(const unsigned char* g, unsigned char* l) {
  __builtin_amdgcn_global_load_lds((const __attribute__((address_space(1))) void*)g,
                                   (__attribute__((address_space(3))) void*)l, 16, 0, 0);
}

// One wave per row of x: quantize RAW x to fp8 e4m3 (norms divided out in the
// GEMM epilogue), emit nx[row] = |x_row|. (Proven in R6-R9, absmax pass.)
__global__ __launch_bounds__(256) void xquant(const float* __restrict__ x,
                                              unsigned char* __restrict__ xq,
                                              float* __restrict__ nx) {
  int wave = threadIdx.x >> 6;
  int lane = threadIdx.x & 63;
  int row = blockIdx.x * 4 + wave;           // 512 rows, 128 blocks
  const float4* src = (const float4*)(x + (size_t)row * DIM);
  float4 v0 = src[2 * lane];
  float4 v1 = src[2 * lane + 1];
  float ss = v0.x*v0.x + v0.y*v0.y + v0.z*v0.z + v0.w*v0.w
           + v1.x*v1.x + v1.y*v1.y + v1.z*v1.z + v1.w*v1.w;
  #pragma unroll
  for (int off = 32; off > 0; off >>= 1) ss += __shfl_xor(ss, off, 64);
  int p0 = __builtin_amdgcn_cvt_pk_fp8_f32(v0.x, v0.y, 0, false);
  p0     = __builtin_amdgcn_cvt_pk_fp8_f32(v0.z, v0.w, p0, true);
  int p1 = __builtin_amdgcn_cvt_pk_fp8_f32(v1.x, v1.y, 0, false);
  p1     = __builtin_amdgcn_cvt_pk_fp8_f32(v1.z, v1.w, p1, true);
  ((int2*)(xq + (size_t)row * DIM))[lane] = make_int2(p0, p1);
  if (lane == 0) nx[row] = fmaxf(sqrtf(ss), 1e-12f);
}

// Fused wt-quantize + 512x64 fp8 GEMM + CosFace epilogue.
// Combines the two proven-necessary properties that no prior round had both
// of: wt read ONCE chip-wide (205 MB = 33 us HBM floor; R7's x2 duplication
// removed) AND 2 blocks/CU occupancy (R9's 1-blk/CU lockstep removed).
// 512 threads = 8 waves (4m x 1n... wm 0..3 over 512 rows => per-wave
// 128x32), acc[8][2] = 64 AGPR + ~50 arch = R7's exact no-spill envelope
// at (512,4). LDS: A dbuf 2x32K (xq, full 512 rows x BK=64) + B dbuf 2x4K
// + misc ~= 81 KB -> 2 blocks/CU.
// Per K-tile (BK=64, 8 iters, R7's proven 3-stage B pipeline, ONE barrier):
//   ds_write B(kk+1) [other half] -> stage A(kk+1) asyncs [other half] ->
//   issue B-loads f(kk+2) -> 32 MFMA -> quant f(kk+2) -> __syncthreads.
// LDS placement: content granule g (8B) of row r sits at position
// g ^ (((r>>1)&3)<<1) -- 16B-chunk-preserving (async-copy compatible) and
// spreads the 64-lane b64 fragment reads evenly (4-way structural minimum,
// no excess serialization). Staging and read sides verified algebraically
// to use the identical permutation.
__global__ __launch_bounds__(512, 4) void cosface_fused(
    const unsigned char* __restrict__ xq,
    const float* __restrict__ wt,
    const int* __restrict__ gt,
    const float* __restrict__ nx,
    float* __restrict__ partial,
    float* __restrict__ tgt) {
  __shared__ __align__(16) unsigned char lds_a[2][512 * 64];  // 64 KB
  __shared__ __align__(16) unsigned char lds_b[2][BN * 64];   //  8 KB
  __shared__ float lds_rowsum[512];
  __shared__ float lds_nx[512];
  __shared__ float lds_nw[BN];
  __shared__ int lds_gt[512];

  const int tid = threadIdx.x;
  const int lane = tid & 63;
  const int w = tid >> 6;          // wave 0..7
  const int wm = w >> 1;           // 0..3  (128-row slice)
  const int wn_ = w & 1;           // 0..1  (32-col slice)
  const int nt = blockIdx.x;       // 0..1562

  lds_rowsum[tid] = 0.f;           // 512 threads cover all 512 rows
  lds_gt[tid] = gt[tid];
  lds_nx[tid] = nx[tid];

  // A staging (xq, L2-resident): per K-tile 2048 chunks of 16B, 4/thread.
  // chunk c: row m = c>>2, position-chunk qs = c&3, CONTENT chunk
  // qc = qs ^ ((m>>1)&3)  (granule position p = g ^ (((m>>1)&3)<<1)).
  unsigned int oa[4];
  #pragma unroll
  for (int j = 0; j < 4; ++j) {
    int c = j * 512 + tid;
    int m = c >> 2;
    int qc = (c & 3) ^ ((m >> 1) & 3);
    oa[j] = (unsigned int)m * DIM + qc * 16;
  }
#define STAGEA(sel, kk) do {                                                 \
    _Pragma("unroll")                                                        \
    for (int j = 0; j < 4; ++j)                                              \
      async_copy16(xq + oa[j] + (kk) * 64,                                   \
                   &lds_a[sel][(j * 512 + w * 64) * 16]);                    \
  } while (0)

  // B source (fp32 wt): thread owns granule g0 (8 k-values) of row r0.
  const int r0 = tid >> 3;                 // class row 0..63
  const int g0 = tid & 7;                  // k-granule within BK=64
  int rowB = nt * BN + r0;
  if (rowB >= CCLS) rowB = CCLS - 1;       // clamp; excluded in epilogue
  const float* wsrc = wt + (size_t)rowB * DIM + g0 * 8;
  const int pb_off = r0 * 64 + (g0 ^ (((r0 >> 1) & 3) << 1)) * 8;

#define LOADB(K) do {                                                        \
    const float* p_ = wsrc + (K) * 64;                                       \
    f0 = *(const float4*)(p_);                                               \
    f1 = *(const float4*)(p_ + 4);                                           \
  } while (0)

#define QUANT8() do {                                                        \
    f0.x*=16.f; f0.y*=16.f; f0.z*=16.f; f0.w*=16.f;                          \
    f1.x*=16.f; f1.y*=16.f; f1.z*=16.f; f1.w*=16.f;                          \
    ssq += f0.x*f0.x + f0.y*f0.y + f0.z*f0.z + f0.w*f0.w                     \
         + f1.x*f1.x + f1.y*f1.y + f1.z*f1.z + f1.w*f1.w;                    \
    int q0_ = __builtin_amdgcn_cvt_pk_fp8_f32(f0.x, f0.y, 0, false);         \
    q0_     = __builtin_amdgcn_cvt_pk_fp8_f32(f0.z, f0.w, q0_, true);        \
    int q1_ = __builtin_amdgcn_cvt_pk_fp8_f32(f1.x, f1.y, 0, false);         \
    q1_     = __builtin_amdgcn_cvt_pk_fp8_f32(f1.z, f1.w, q1_, true);        \
    pq = make_int2(q0_, q1_);                                                \
  } while (0)

  f32x4 acc[8][2];
  #pragma unroll
  for (int i = 0; i < 8; ++i)
    #pragma unroll
    for (int j = 0; j < 2; ++j)
      acc[i][j] = (f32x4){0.f, 0.f, 0.f, 0.f};

  const int quad = lane >> 4;
  const int l15 = lane & 15;
  const int swg = ((l15 >> 1) & 3) << 1;   // granule-XOR: row = base(x16)+l15
  float4 f0, f1;
  int2 pq;
  float ssq = 0.f;

  // ---- Prologue: A(0) asyncs; B(0) quant+write; B(1) quant into regs.
  STAGEA(0, 0);
  LOADB(0); QUANT8();
  *(int2*)&lds_b[0][pb_off] = pq;
  LOADB(1); QUANT8();
  __syncthreads();   // drains A(0) asyncs + B(0) ds_writes; init visible

  #pragma unroll
  for (int kk = 0; kk < 8; ++kk) {
    const int cur = kk & 1;
    if (kk < 7) {
      *(int2*)&lds_b[cur ^ 1][pb_off] = pq;   // publish B(kk+1)
      STAGEA(cur ^ 1, kk + 1);                // stage A(kk+1)
    }
    if (kk < 6) LOADB(kk + 2);                // issue f(kk+2) early

    // Compute tile kk: per s, granule g = s*4+quad at pos g^swg.
    #pragma unroll
    for (int s = 0; s < 2; ++s) {
      const int off = (((s * 4 + quad) ^ swg) << 3);
      long long af[8], bf[2];
      #pragma unroll
      for (int i = 0; i < 8; ++i)
        af[i] = *(const long long*)&lds_a[cur][(wm * 128 + i * 16 + l15) * 64 + off];
      #pragma unroll
      for (int j = 0; j < 2; ++j)
        bf[j] = *(const long long*)&lds_b[cur][(wn_ * 32 + j * 16 + l15) * 64 + off];
      #pragma unroll
      for (int i = 0; i < 8; ++i)
        #pragma unroll
        for (int j = 0; j < 2; ++j)
          acc[i][j] = __builtin_amdgcn_mfma_f32_16x16x32_fp8_fp8(af[i], bf[j], acc[i][j], 0, 0, 0);
    }

    if (kk < 6) QUANT8();                     // loads covered by MFMA phase
    if (kk < 7) __syncthreads();
  }
#undef STAGEA
#undef LOADB
#undef QUANT8

  // ---- nw: 8-lane group reduce, plain store (one owner per class row).
  ssq += __shfl_xor(ssq, 1, 64);
  ssq += __shfl_xor(ssq, 2, 64);
  ssq += __shfl_xor(ssq, 4, 64);
  if ((lane & 7) == 0) lds_nw[r0] = ssq;
  __syncthreads();

  // ---- Epilogue: cos = acc/(|16w|*|x|); logit = 64*cos (-22.4 at gt);
  // rowsum += sum_n exp(logit-64).
  float rnw[2];
  #pragma unroll
  for (int j = 0; j < 2; ++j)
    rnw[j] = 1.0f / fmaxf(sqrtf(lds_nw[wn_ * 32 + j * 16 + l15]), 1e-12f);
  #pragma unroll
  for (int i = 0; i < 8; ++i) {
    #pragma unroll
    for (int reg = 0; reg < 4; ++reg) {
      int m_loc = wm * 128 + i * 16 + quad * 4 + reg;
      int gtm = lds_gt[m_loc];
      float rx = 64.0f / lds_nx[m_loc];     // fold SCALE into the division
      float s = 0.f;
      #pragma unroll
      for (int j = 0; j < 2; ++j) {
        int n_g = nt * BN + wn_ * 32 + j * 16 + l15;
        float logit = acc[i][j][reg] * rnw[j] * rx;
        if (n_g == gtm) {
          logit -= 64.f * 0.35f;
          tgt[m_loc] = logit;
        }
        if (n_g < CCLS) s += __expf(logit - 64.f);
      }
      #pragma unroll
      for (int off = 1; off < 16; off <<= 1) s += __shfl_xor(s, off, 64);
      if (l15 == 0) atomicAdd(&lds_rowsum[m_loc], s);
    }
  }
  __syncthreads();
  partial[(size_t)tid * NT + nt] = lds_rowsum[tid];
}

// One wave per row m: sum partial[m][0..NT) (contiguous), emit nll[m].
__global__ __launch_bounds__(64) void nll_rows(const float* __restrict__ partial,
                                               const float* __restrict__ tgt,
                                               float* __restrict__ nll) {
  int m = blockIdx.x;
  int lane = threadIdx.x;
  const float* row = partial + (size_t)m * NT;
  float s = 0.f;
  for (int t = lane; t < NT; t += 64) s += row[t];
  #pragma unroll
  for (int off = 32; off > 0; off >>= 1) s += __shfl_xor(s, off, 64);
  if (lane == 0) nll[m] = (logf(s) + 64.f) - tgt[m];
}

__global__ __launch_bounds__(512) void reduce_mean(const float* __restrict__ nll,
                                                   float* __restrict__ out) {
  __shared__ float red[BATCH];
  int m = threadIdx.x;
  red[m] = nll[m];
  __syncthreads();
  for (int k = 256; k > 0; k >>= 1) {
    if (m < k) red[m] += red[m + k];
    __syncthreads();
  }
  if (m == 0) out[0] = red[0] * (1.0f / BATCH);
}

extern "C" void kernel_launch(void* const* d_in, const int* in_sizes, int n_in,
                              void* d_out, int out_size, void* d_ws, size_t ws_size,
                              hipStream_t stream) {
  const float* x  = (const float*)d_in[0];
  const int*   gt = (const int*)d_in[1];
  const float* wt = (const float*)d_in[2];
  float* out = (float*)d_out;

  char* ws = (char*)d_ws;
  unsigned char* xq = (unsigned char*)ws;            //   262,144 B
  float* nx         = (float*)(ws + 262144);         //     2,048 B
  float* partial    = (float*)(ws + 264192);         // 3,201,024 B (512*1563*4)
  float* tgt        = (float*)(ws + 3465216);        //     2,048 B
  float* nll        = (float*)(ws + 3467264);        //     2,048 B

  xquant<<<BATCH / 4, 256, 0, stream>>>(x, xq, nx);
  cosface_fused<<<NT, 512, 0, stream>>>(xq, wt, gt, nx, partial, tgt);
  nll_rows<<<BATCH, 64, 0, stream>>>(partial, tgt, nll);
  reduce_mean<<<1, BATCH, 0, stream>>>(nll, out);
}